// Round 2
// baseline (313.411 us; speedup 1.0000x reference)
//
#include <hip/hip_runtime.h>
#include <hip/hip_fp16.h>

// out[s,n] = sum_c w0[s,c]*comp[c][n+d] + w1[s,c]*comp[c][n+d+1],
//   d = floor(shift[s,c]), frac = shift - d constant across n.
// Components staged in LDS as packed half2 words, zero-padded, with a
// +1-word-per-8 swizzle (addr = u + (u>>3)) so the lane stride of 4 words
// lands 2 lanes/bank (free). The whole shift goes into the LDS address;
// only the half-parity remains, handled branch-free with v_alignbit+cndmask.
//
// R2 (retry of R1 — container-level infra failure, no kernel evidence):
// latency theory: R0 kernel was latency-bound, nothing saturated
// (VALUBusy 40%, HBM 17%, MfmaUtil 0, Occupancy 34%). Occupancy was capped
// by LDS at 4 blocks/CU x 4 waves = 16 waves/CU. Now: block=1024, kM=32,
// grid=512 -> 2 blocks/CU x 16 waves = 32 waves/CU (100% ceiling), needs
// VGPR<=64 (R0 body compiled at exactly 64 *with* 16 prefetch regs that
// are now deleted). Also: contrib/shift staged into LDS once at block
// start (vector global loads) instead of per-si uniform loads -> no SMEM
// s_load in the main loop, so lgkmcnt waits cover only ~120cy LDS ops
// instead of draining in-flight L2/HBM scalar loads each si iteration.
// Inner c-loop math is byte-identical to the 297us version.

namespace {
constexpr int kS     = 16384;
constexpr int kN     = 2048;
constexpr int kC     = 8;
constexpr int kM     = 32;     // samples per block -> 512 blocks = 2/CU
constexpr int kBlock = 1024;   // 16 waves/block
constexpr int kPadH  = 32;     // left zero-pad (halves); d clamped to [-31,31]
constexpr int kUnits = 1057;   // half2 words per row (2114 halves >= 32+2048+34)
constexpr int kRowStride = 1192; // swizzled b32 footprint per row (max swz=1188)

__device__ __forceinline__ int swz(int u) { return u + (u >> 3); }

__global__ __launch_bounds__(kBlock, 8)
void smf_kernel(const float* __restrict__ comps,
                const float* __restrict__ contrib,
                const float* __restrict__ shift,
                float* __restrict__ out)
{
    __shared__ uint32_t ldsU[kC * kRowStride];   // 38144 B
    __shared__ float    ctLds[kM * kC];          // 1024 B
    __shared__ float    shLds[kM * kC];          // 1024 B  -> 40192 B total

    const int tid = threadIdx.x;
    const int s0  = blockIdx.x * kM;

    // ---- Stage components -> LDS as half2 words, zero-padded, swizzled ----
    for (int c = 0; c < kC; ++c) {
        const float* src = comps + c * kN;
        uint32_t* dst = ldsU + c * kRowStride;
        for (int u = tid; u < kUnits; u += kBlock) {
            const int j = 2 * u - kPadH;             // even source index
            float2 v = make_float2(0.f, 0.f);
            if (j >= 0 && j < kN - 1) v = *reinterpret_cast<const float2*>(src + j);
            __half2 h2 = __floats2half2_rn(v.x, v.y);
            dst[swz(u)] = *reinterpret_cast<const uint32_t*>(&h2);
        }
    }

    // ---- Stage this block's contrib/shift rows (kM*kC floats = 64 float4 each) ----
    for (int t = tid; t < (kM * kC) / 2; t += kBlock) {
        if (t < (kM * kC) / 4) {
            reinterpret_cast<float4*>(ctLds)[t] =
                reinterpret_cast<const float4*>(contrib + (size_t)s0 * kC)[t];
        } else {
            const int t2 = t - (kM * kC) / 4;
            reinterpret_cast<float4*>(shLds)[t2] =
                reinterpret_cast<const float4*>(shift + (size_t)s0 * kC)[t2];
        }
    }
    __syncthreads();

    const int q  = tid >> 8;          // 0..3: which sample-subrange
    const int n0 = (tid & 255) * 8;   // 8 outputs per lane covers N=2048

    #pragma unroll 1
    for (int r = 0; r < kM / 4; ++r) {
        const int si = q * (kM / 4) + r;
        const int s  = s0 + si;

        // uniform-address LDS reads -> broadcast, no bank conflicts
        const float4 ccA = *reinterpret_cast<const float4*>(ctLds + si * kC);
        const float4 ccB = *reinterpret_cast<const float4*>(ctLds + si * kC + 4);
        const float4 csA = *reinterpret_cast<const float4*>(shLds + si * kC);
        const float4 csB = *reinterpret_cast<const float4*>(shLds + si * kC + 4);

        const float ct[8] = {ccA.x, ccA.y, ccA.z, ccA.w, ccB.x, ccB.y, ccB.z, ccB.w};
        const float sh[8] = {csA.x, csA.y, csA.z, csA.w, csB.x, csB.y, csB.z, csB.w};

        float acc[8];
        #pragma unroll
        for (int k = 0; k < 8; ++k) acc[k] = 0.f;

        #pragma unroll
        for (int c = 0; c < kC; ++c) {
            const float fl = floorf(sh[c]);
            const float fr = sh[c] - fl;              // in [0,1)
            int d = (int)fl;
            d = d < -31 ? -31 : (d > 31 ? 31 : d);    // LDS safety; dataset |d|<=16
            const float w1 = ct[c] * fr;
            const float w0 = ct[c] - w1;              // ct*(1-fr)

            const int a   = n0 + d + kPadH;           // padded half index of x0
            const int u0  = a >> 1;
            const bool odd = (a & 1) != 0;

            const uint32_t* row = ldsU + c * kRowStride;
            const uint32_t y0 = row[swz(u0 + 0)];
            const uint32_t y1 = row[swz(u0 + 1)];
            const uint32_t y2 = row[swz(u0 + 2)];
            const uint32_t y3 = row[swz(u0 + 3)];
            const uint32_t y4 = row[swz(u0 + 4)];
            const uint32_t y5 = row[swz(u0 + 5)];

            // z_m holds halves (x_{2m}, x_{2m+1}); odd-parity realign = funnel>>16
            const uint32_t z0 = odd ? __builtin_amdgcn_alignbit(y1, y0, 16) : y0;
            const uint32_t z1 = odd ? __builtin_amdgcn_alignbit(y2, y1, 16) : y1;
            const uint32_t z2 = odd ? __builtin_amdgcn_alignbit(y3, y2, 16) : y2;
            const uint32_t z3 = odd ? __builtin_amdgcn_alignbit(y4, y3, 16) : y3;
            const uint32_t z4 = odd ? __builtin_amdgcn_alignbit(y5, y4, 16) : y4;

            const float2 f0 = __half22float2(*reinterpret_cast<const __half2*>(&z0));
            const float2 f1 = __half22float2(*reinterpret_cast<const __half2*>(&z1));
            const float2 f2 = __half22float2(*reinterpret_cast<const __half2*>(&z2));
            const float2 f3 = __half22float2(*reinterpret_cast<const __half2*>(&z3));
            const float2 f4 = __half22float2(*reinterpret_cast<const __half2*>(&z4));

            acc[0] += w0 * f0.x + w1 * f0.y;
            acc[1] += w0 * f0.y + w1 * f1.x;
            acc[2] += w0 * f1.x + w1 * f1.y;
            acc[3] += w0 * f1.y + w1 * f2.x;
            acc[4] += w0 * f2.x + w1 * f2.y;
            acc[5] += w0 * f2.y + w1 * f3.x;
            acc[6] += w0 * f3.x + w1 * f3.y;
            acc[7] += w0 * f3.y + w1 * f4.x;
        }

        float4* orow = reinterpret_cast<float4*>(out + (size_t)s * kN + n0);
        orow[0] = make_float4(acc[0], acc[1], acc[2], acc[3]);
        orow[1] = make_float4(acc[4], acc[5], acc[6], acc[7]);
    }
}
} // namespace

extern "C" void kernel_launch(void* const* d_in, const int* in_sizes, int n_in,
                              void* d_out, int out_size, void* d_ws, size_t ws_size,
                              hipStream_t stream) {
    // inputs: [0]=inputs (unused by reference), [1]=components,
    // [2]=contributions, [3]=shift. Output: float32 [S, N].
    const float* comps   = (const float*)d_in[1];
    const float* contrib = (const float*)d_in[2];
    const float* shiftp  = (const float*)d_in[3];
    float* out = (float*)d_out;

    dim3 grid(kS / kM);    // 512 blocks -> 2 resident per CU, 32 waves/CU
    dim3 block(kBlock);
    smf_kernel<<<grid, block, 0, stream>>>(comps, contrib, shiftp, out);
}

// Round 3
// 285.536 us; speedup vs baseline: 1.0976x; 1.0976x over previous
//
#include <hip/hip_runtime.h>
#include <hip/hip_fp16.h>

// out[s,n] = sum_c w0[s,c]*comp[c][n+d] + w1[s,c]*comp[c][n+d+1],
//   d = floor(shift[s,c]), frac = shift - d constant across n.
// Components staged in LDS as packed half2 words, zero-padded, swizzled
// (addr = u + (u>>3)). Shift folds into the LDS address; half-parity is
// handled branch-free with v_alignbit+cndmask.
//
// R3 theory: R2 (1024thr/kM32) doubled occupancy but HBM traffic exploded:
// FETCH 10->106 MB (~80% of the *output* read back), WRITE 156->312 MB
// (2.3x output). Signature of partial-line write-allocate/RMW: each lane's
// two dwordx4 stores cover only half of every 32B sector they touch
// (16B at 32B stride), and with 8 concurrent output rows/CU the lines get
// evicted before completion -> fetch-for-merge + double eviction.
// Fix: (a) FULL-LINE stores — lane t writes float4 at n=4t and n=1024+4t,
// so every store instruction fully covers 8x128B lines (8 contiguous
// lanes/line, whole sectors). Same 6 ds_read per c (both 4-output groups
// share d/parity; 3 words each). (b) 512-thread blocks, kM=16, grid=1024:
// 4 blocks/CU x 8 waves = 32 waves/CU (100% ceiling), LDS 39.4KB*4 =
// 157.7KB <= 160KB, only 2 concurrent rows/block. contrib/shift stay
// LDS-staged (no SMEM drains in the loop).

namespace {
constexpr int kS     = 16384;
constexpr int kN     = 2048;
constexpr int kC     = 8;
constexpr int kM     = 16;     // samples per block -> 1024 blocks = 4/CU
constexpr int kBlock = 512;    // 8 waves/block
constexpr int kPadH  = 32;     // left zero-pad (halves); d clamped to [-31,31]
constexpr int kUnits = 1057;   // half2 words per row (2114 halves >= 32+2048+34)
constexpr int kRowStride = 1192; // swizzled b32 footprint per row (max swz=1188)

__device__ __forceinline__ int swz(int u) { return u + (u >> 3); }

__global__ __launch_bounds__(kBlock, 8)
void smf_kernel(const float* __restrict__ comps,
                const float* __restrict__ contrib,
                const float* __restrict__ shift,
                float* __restrict__ out)
{
    __shared__ uint32_t ldsU[kC * kRowStride];   // 38144 B
    __shared__ float    ctLds[kM * kC];          // 512 B
    __shared__ float    shLds[kM * kC];          // 512 B  -> 39168 B total

    const int tid = threadIdx.x;
    const int s0  = blockIdx.x * kM;

    // ---- Stage components -> LDS as half2 words, zero-padded, swizzled ----
    for (int c = 0; c < kC; ++c) {
        const float* src = comps + c * kN;
        uint32_t* dst = ldsU + c * kRowStride;
        for (int u = tid; u < kUnits; u += kBlock) {
            const int j = 2 * u - kPadH;             // even source index
            float2 v = make_float2(0.f, 0.f);
            if (j >= 0 && j < kN - 1) v = *reinterpret_cast<const float2*>(src + j);
            __half2 h2 = __floats2half2_rn(v.x, v.y);
            dst[swz(u)] = *reinterpret_cast<const uint32_t*>(&h2);
        }
    }

    // ---- Stage this block's contrib/shift rows (kM*kC = 128 floats each) ----
    for (int tt = tid; tt < (kM * kC) / 2; tt += kBlock) {   // 64 float4 total
        if (tt < (kM * kC) / 4) {
            reinterpret_cast<float4*>(ctLds)[tt] =
                reinterpret_cast<const float4*>(contrib + (size_t)s0 * kC)[tt];
        } else {
            const int t2 = tt - (kM * kC) / 4;
            reinterpret_cast<float4*>(shLds)[t2] =
                reinterpret_cast<const float4*>(shift + (size_t)s0 * kC)[t2];
        }
    }
    __syncthreads();

    const int q = tid >> 8;           // 0..1: which sample-subrange
    const int t = tid & 255;          // lane within q-group

    #pragma unroll 1
    for (int r = 0; r < kM / 2; ++r) {
        const int si = q * (kM / 2) + r;
        const int s  = s0 + si;

        // uniform-address LDS reads -> broadcast, no bank conflicts
        const float4 ccA = *reinterpret_cast<const float4*>(ctLds + si * kC);
        const float4 ccB = *reinterpret_cast<const float4*>(ctLds + si * kC + 4);
        const float4 csA = *reinterpret_cast<const float4*>(shLds + si * kC);
        const float4 csB = *reinterpret_cast<const float4*>(shLds + si * kC + 4);

        const float ct[8] = {ccA.x, ccA.y, ccA.z, ccA.w, ccB.x, ccB.y, ccB.z, ccB.w};
        const float sh[8] = {csA.x, csA.y, csA.z, csA.w, csB.x, csB.y, csB.z, csB.w};

        float accA[4], accB[4];
        #pragma unroll
        for (int k = 0; k < 4; ++k) { accA[k] = 0.f; accB[k] = 0.f; }

        #pragma unroll
        for (int c = 0; c < kC; ++c) {
            const float fl = floorf(sh[c]);
            const float fr = sh[c] - fl;              // in [0,1)
            int d = (int)fl;
            d = d < -31 ? -31 : (d > 31 ? 31 : d);    // LDS safety; dataset |d|<=16
            const float w1 = ct[c] * fr;
            const float w0 = ct[c] - w1;              // ct*(1-fr)

            // group A covers n = 4t..4t+3, group B covers n+1024 (same
            // d and parity; word offset exactly +512).
            const int a   = 4 * t + d + kPadH;        // padded half index of x0
            const int u0  = a >> 1;
            const bool odd = (a & 1) != 0;

            const uint32_t* row = ldsU + c * kRowStride;
            const uint32_t yA0 = row[swz(u0 + 0)];
            const uint32_t yA1 = row[swz(u0 + 1)];
            const uint32_t yA2 = row[swz(u0 + 2)];
            const uint32_t yB0 = row[swz(u0 + 512)];
            const uint32_t yB1 = row[swz(u0 + 513)];
            const uint32_t yB2 = row[swz(u0 + 514)];

            // z holds halves (x_a, x_a+1) etc; odd-parity realign = funnel>>16
            const uint32_t zA0 = odd ? __builtin_amdgcn_alignbit(yA1, yA0, 16) : yA0;
            const uint32_t zA1 = odd ? __builtin_amdgcn_alignbit(yA2, yA1, 16) : yA1;
            const uint32_t zA2 = odd ? (yA2 >> 16) : yA2;   // only low half used
            const uint32_t zB0 = odd ? __builtin_amdgcn_alignbit(yB1, yB0, 16) : yB0;
            const uint32_t zB1 = odd ? __builtin_amdgcn_alignbit(yB2, yB1, 16) : yB1;
            const uint32_t zB2 = odd ? (yB2 >> 16) : yB2;

            const float2 fA0 = __half22float2(*reinterpret_cast<const __half2*>(&zA0));
            const float2 fA1 = __half22float2(*reinterpret_cast<const __half2*>(&zA1));
            const float2 fA2 = __half22float2(*reinterpret_cast<const __half2*>(&zA2));
            const float2 fB0 = __half22float2(*reinterpret_cast<const __half2*>(&zB0));
            const float2 fB1 = __half22float2(*reinterpret_cast<const __half2*>(&zB1));
            const float2 fB2 = __half22float2(*reinterpret_cast<const __half2*>(&zB2));

            accA[0] += w0 * fA0.x + w1 * fA0.y;
            accA[1] += w0 * fA0.y + w1 * fA1.x;
            accA[2] += w0 * fA1.x + w1 * fA1.y;
            accA[3] += w0 * fA1.y + w1 * fA2.x;
            accB[0] += w0 * fB0.x + w1 * fB0.y;
            accB[1] += w0 * fB0.y + w1 * fB1.x;
            accB[2] += w0 * fB1.x + w1 * fB1.y;
            accB[3] += w0 * fB1.y + w1 * fB2.x;
        }

        // Full-line stores: each wave's store covers 8x128B lines completely.
        float* orow = out + (size_t)s * kN;
        *reinterpret_cast<float4*>(orow + 4 * t) =
            make_float4(accA[0], accA[1], accA[2], accA[3]);
        *reinterpret_cast<float4*>(orow + 1024 + 4 * t) =
            make_float4(accB[0], accB[1], accB[2], accB[3]);
    }
}
} // namespace

extern "C" void kernel_launch(void* const* d_in, const int* in_sizes, int n_in,
                              void* d_out, int out_size, void* d_ws, size_t ws_size,
                              hipStream_t stream) {
    // inputs: [0]=inputs (unused by reference), [1]=components,
    // [2]=contributions, [3]=shift. Output: float32 [S, N].
    const float* comps   = (const float*)d_in[1];
    const float* contrib = (const float*)d_in[2];
    const float* shiftp  = (const float*)d_in[3];
    float* out = (float*)d_out;

    dim3 grid(kS / kM);    // 1024 blocks -> 4 resident per CU, 32 waves/CU
    dim3 block(kBlock);
    smf_kernel<<<grid, block, 0, stream>>>(comps, contrib, shiftp, out);
}